// Round 7
// baseline (234.339 us; speedup 1.0000x reference)
//
#include <hip/hip_runtime.h>
#include <hip/hip_bf16.h>
#include <math.h>

#define BB 2
#define TT 2048
#define CC 1024
#define HH 16
#define DD 64
#define C3 3072
#define BT 4096

typedef __attribute__((ext_vector_type(8))) short short8;
typedef __attribute__((ext_vector_type(8))) unsigned short ushort8;
typedef __attribute__((ext_vector_type(4))) unsigned short ushort4v;
typedef __attribute__((ext_vector_type(4))) float floatx4;

// fp32 -> bf16, round-to-nearest-even
__device__ __forceinline__ unsigned short f2b(float f) {
    union { float f; unsigned int u; } v; v.f = f;
    unsigned int u = v.u;
    unsigned int r = (u + 0x7fffu + ((u >> 16) & 1u)) >> 16;
    return (unsigned short)r;
}
// cheap round-half-up (for P weights; positive values)
__device__ __forceinline__ unsigned short f2b_fast(float f) {
    unsigned int u = __builtin_bit_cast(unsigned int, f);
    return (unsigned short)((u + 0x8000u) >> 16);
}

__device__ __forceinline__ void store_out(unsigned short* p, float v) { *p = f2b(v); }
__device__ __forceinline__ void store_out(float* p, float v) { *p = v; }

// async 16B global -> LDS (lane-linear dest: wave-uniform base + lane*16)
__device__ __forceinline__ void async16(const unsigned short* g, unsigned short* lds) {
    __builtin_amdgcn_global_load_lds(
        (const __attribute__((address_space(1))) unsigned int*)g,
        (__attribute__((address_space(3))) unsigned int*)lds, 16, 0, 0);
}

// ---------------------------------------------------------------------------
// Prep kernel: blocks 0..2047 cast x fp32->bf16 (8 elems/thread);
// blocks 2048..3071 transpose+cast the two weight matrices (64x64 tiles).
// ---------------------------------------------------------------------------
__global__ __launch_bounds__(256) void prep_kernel(
    const float* __restrict__ x, unsigned short* __restrict__ xb,
    const float* __restrict__ Wqkv, const float* __restrict__ Wproj,
    unsigned short* __restrict__ Wqkv_t, unsigned short* __restrict__ Wproj_t)
{
    __shared__ float tile[64 * 65];
    const int tid = threadIdx.x;
    const int bid = blockIdx.x;

    if (bid < 2048) {                      // ---- cast x ----
        int i = bid * 256 + tid;
        const float4 v0 = *(const float4*)&x[(size_t)i * 8];
        const float4 v1 = *(const float4*)&x[(size_t)i * 8 + 4];
        ushort8 pk;
        pk[0] = f2b(v0.x); pk[1] = f2b(v0.y); pk[2] = f2b(v0.z); pk[3] = f2b(v0.w);
        pk[4] = f2b(v1.x); pk[5] = f2b(v1.y); pk[6] = f2b(v1.z); pk[7] = f2b(v1.w);
        *(ushort8*)&xb[(size_t)i * 8] = pk;
        return;
    }

    // ---- weight transposes ----
    const int xt = bid - 2048;             // 0..1023
    const int cxt = xt & 63;               // col-tile
    const int r0  = (xt >> 6) * 64;        // row-tile base
    const float* src; unsigned short* dst; int Ccols, c0;
    if (cxt < 48) { src = Wqkv;  dst = Wqkv_t;  Ccols = C3; c0 = cxt * 64; }
    else          { src = Wproj; dst = Wproj_t; Ccols = CC; c0 = (cxt - 48) * 64; }
#pragma unroll
    for (int it = 0; it < 4; it++) {
        int idx = it * 256 + tid;
        int row = idx >> 4;
        int c4  = idx & 15;
        float4 v = *(const float4*)&src[(size_t)(r0 + row) * Ccols + c0 + c4 * 4];
        tile[row * 65 + c4 * 4 + 0] = v.x;
        tile[row * 65 + c4 * 4 + 1] = v.y;
        tile[row * 65 + c4 * 4 + 2] = v.z;
        tile[row * 65 + c4 * 4 + 3] = v.w;
    }
    __syncthreads();
#pragma unroll
    for (int it = 0; it < 2; it++) {
        int idx = it * 256 + tid;
        int orow = idx >> 3;
        int o8   = idx & 7;
        ushort8 pk;
#pragma unroll
        for (int j = 0; j < 8; j++) pk[j] = f2b(tile[(o8 * 8 + j) * 65 + orow]);
        *(ushort8*)&dst[(size_t)(c0 + orow) * CC + r0 + o8 * 8] = pk;
    }
}

// ---------------------------------------------------------------------------
// bf16 GEMM, B transposed: 128x128, BK=64, XOR chunk swizzle.
// FRAG mode (QKV GEMM): write Q/K/V directly in MFMA-fragment order so
// attention reads are lane-contiguous 1KB chunks:
//   Qf/Kf[((bh*128 + tok/16)*2 + d/32)*512 + ((d/8)%4)*128 + (tok%16)*8 + d%8]
//   Vf  [((bh*64 + tok/32)*4 + d/16)*512 + ((tok/4)%4*16 + d%16)*8
//        + ((tok/16)%2)*4 + tok%4]     (key-slot permutation folded in)
// Q is pre-scaled by log2(e)/8.
// ---------------------------------------------------------------------------
template <typename OUT_T, bool FRAG>
__global__ __launch_bounds__(256) void gemm_bt_kernel(
    const unsigned short* __restrict__ A, const unsigned short* __restrict__ Bm,
    const float* __restrict__ bias, OUT_T* __restrict__ Cmat,
    unsigned short* __restrict__ Qf, unsigned short* __restrict__ Kf,
    unsigned short* __restrict__ Vf,
    int M, int N, int K, float qscale)
{
    __shared__ __align__(16) unsigned short sA[128 * 64];
    __shared__ __align__(16) unsigned short sB[128 * 64];

    const int tid = threadIdx.x;
    const int lane16 = tid & 15, quad = (tid & 63) >> 4;
    const int w = tid >> 6;
    const int wm = w >> 1, wn = w & 1;
    const int m0 = blockIdx.y * 128, n0 = blockIdx.x * 128;
    const int lx = lane16 & 7;

    floatx4 acc[4][4] = {};

    for (int kt = 0; kt < K; kt += 64) {
#pragma unroll
        for (int it = 0; it < 4; it++) {
            int idx = it * 256 + tid;
            int row = idx >> 3;
            int c8m = (idx & 7) ^ (row & 7);
            int wslot = it * 256 + (tid & 192);
            async16(&A[(size_t)(m0 + row) * K + kt + c8m * 8], &sA[wslot * 8]);
            async16(&Bm[(size_t)(n0 + row) * K + kt + c8m * 8], &sB[wslot * 8]);
        }
        __syncthreads();
#pragma unroll
        for (int ks = 0; ks < 64; ks += 32) {
            const int slot = ((ks >> 3) + quad) ^ lx;
            short8 af[4], bf[4];
#pragma unroll
            for (int t = 0; t < 4; t++) {
                af[t] = *(const short8*)&sA[(wm * 64 + t * 16 + lane16) * 64 + slot * 8];
                bf[t] = *(const short8*)&sB[(wn * 64 + t * 16 + lane16) * 64 + slot * 8];
            }
#pragma unroll
            for (int mt = 0; mt < 4; mt++)
#pragma unroll
                for (int nt = 0; nt < 4; nt++)
                    acc[mt][nt] = __builtin_amdgcn_mfma_f32_16x16x32_bf16(
                        af[mt], bf[nt], acc[mt][nt], 0, 0, 0);
        }
        __syncthreads();
    }

#pragma unroll
    for (int mt = 0; mt < 4; mt++) {
#pragma unroll
        for (int nt = 0; nt < 4; nt++) {
            int col = n0 + wn * 64 + nt * 16 + lane16;
            float bv = bias[col];
            int row0 = m0 + wm * 64 + mt * 16 + quad * 4;
            if (!FRAG) {
#pragma unroll
                for (int r = 0; r < 4; r++)
                    store_out(&Cmat[(size_t)(row0 + r) * N + col], acc[mt][nt][r] + bv);
            } else {
                const int breg = row0 >> 11;            // batch
                const int tok0 = row0 & (TT - 1);       // token (4-aligned)
                if (col < CC) {                          // ---- Q (scaled) ----
                    int h = col >> 6, d = col & 63;
                    int bh = breg * HH + h;
                    size_t base = ((size_t)(bh * 128 + (tok0 >> 4)) * 2 + (d >> 5)) * 512
                                + ((d >> 3) & 3) * 128 + (tok0 & 15) * 8 + (d & 7);
#pragma unroll
                    for (int r = 0; r < 4; r++)
                        Qf[base + r * 8] = f2b((acc[mt][nt][r] + bv) * qscale);
                } else if (col < 2 * CC) {               // ---- K ----
                    int c = col - CC;
                    int h = c >> 6, d = c & 63;
                    int bh = breg * HH + h;
                    size_t base = ((size_t)(bh * 128 + (tok0 >> 4)) * 2 + (d >> 5)) * 512
                                + ((d >> 3) & 3) * 128 + (tok0 & 15) * 8 + (d & 7);
#pragma unroll
                    for (int r = 0; r < 4; r++)
                        Kf[base + r * 8] = f2b(acc[mt][nt][r] + bv);
                } else {                                 // ---- V ----
                    int c = col - 2 * CC;
                    int h = c >> 6, d = c & 63;
                    int bh = breg * HH + h;
                    size_t base = ((size_t)(bh * 64 + (tok0 >> 5)) * 4 + (d >> 4)) * 512
                                + (((tok0 >> 2) & 3) * 16 + (d & 15)) * 8
                                + ((tok0 >> 4) & 1) * 4;
                    ushort4v pk;
#pragma unroll
                    for (int r = 0; r < 4; r++) pk[r] = f2b(acc[mt][nt][r] + bv);
                    *(ushort4v*)&Vf[base] = pk;
                }
            }
        }
    }
}

// ---------------------------------------------------------------------------
// Flash attention, R7: one wave per 16-ROW q-tile. Grid (32 bh, 128 j) =
// 4096 single-wave blocks; VGPR capped at 128 via __launch_bounds__(64,4)
// -> 4 waves/SIMD fully resident, zero LDS, zero barriers, no cross-wave
// state (R6's runtime-indexed combine -> 56MB scratch is deleted).
// XCD locality: linear id = bh + 32*j => id%8 = bh%8, so all 128 blocks of
// a head land on one XCD (4 heads/XCD, 2MB K/V in 4MB L2).
// Swapped QK^T (S^T = mfma(K,Q)): lane holds S[key][q=16j+lane16]; P packed
// in-register as PV A-frag (R4-verified math, qg dimension removed).
// Causal mask via global compare: 64t+key_local > 16j+lane16.
// Q pre-scaled by log2(e)/8 in GEMM1 -> raw v_exp_f32 here.
// ---------------------------------------------------------------------------
__global__ __launch_bounds__(64, 4) void attn_mfma_kernel(
    const unsigned short* __restrict__ Qf, const unsigned short* __restrict__ Kf,
    const unsigned short* __restrict__ Vf, unsigned short* __restrict__ att)
{
    const int l = threadIdx.x;                    // 0..63
    const int lane16 = l & 15, quad = l >> 4;
    const int bh = blockIdx.x;                    // same head -> same XCD
    const int b = bh >> 4, h = bh & 15;
    const int j = blockIdx.y;                     // q-rows [16j, 16j+16)

    const unsigned short* Qb = Qf + (size_t)bh * 131072 + l * 8;
    const unsigned short* Kb = Kf + (size_t)bh * 131072 + l * 8;
    const unsigned short* Vb = Vf + (size_t)bh * 131072 + l * 8;

    // Q fragments (B-operand layout: n=lane16=q, k=quad*8+jj=d)
    short8 qf0 = *(const short8*)&Qb[(size_t)(j * 2 + 0) * 512];
    short8 qf1 = *(const short8*)&Qb[(size_t)(j * 2 + 1) * 512];

    floatx4 O[4] = {};                            // [dt]
    float ps = 0.f;                               // row-sum partial
    short8 kfa[8], kfb[8];                        // K frag double buffer

    const int ntiles = (j >> 2) + 1;
    const int qrow = j * 16 + lane16;             // this lane's global q row

#pragma unroll
    for (int i = 0; i < 8; i++)
        kfa[i] = *(const short8*)&Kb[(size_t)i * 512];

    auto body = [&](int t, short8 (&KC)[8], short8 (&KN)[8]) {
        const bool last = (t == ntiles - 1);

        // V fragment loads for this tile (latency hidden under QK+exp)
        short8 vf[8];                             // [kc*4 + dt]
#pragma unroll
        for (int i = 0; i < 8; i++)
            vf[i] = *(const short8*)&Vb[(size_t)(t * 8 + i) * 512];

        // prefetch next tile's K fragments
        if (t + 1 < ntiles) {
#pragma unroll
            for (int i = 0; i < 8; i++)
                KN[i] = *(const short8*)&Kb[(size_t)((t + 1) * 8 + i) * 512];
        }

        // ---- S^T = K Q^T ; p = exp2(s); pack P as PV A-frag words ----
        short8 pa[2];                             // [kc]
#pragma unroll
        for (int nt = 0; nt < 4; nt++) {
            floatx4 s4 = {};
            s4 = __builtin_amdgcn_mfma_f32_16x16x32_bf16(KC[nt * 2 + 0], qf0, s4, 0, 0, 0);
            s4 = __builtin_amdgcn_mfma_f32_16x16x32_bf16(KC[nt * 2 + 1], qf1, s4, 0, 0, 0);
#pragma unroll
            for (int r = 0; r < 4; r++) {
                float v = s4[r];
                if (last) {                       // diag tile: causal mask
                    int key = t * 64 + nt * 16 + quad * 4 + r;
                    if (key > qrow) v = -1e30f;
                }
                float pe = __builtin_amdgcn_exp2f(v);
                ps += pe;
                pa[nt >> 1][(nt & 1) * 4 + r] = (short)f2b_fast(pe);
            }
        }

        // ---- O += P V ----
#pragma unroll
        for (int kc = 0; kc < 2; kc++)
#pragma unroll
            for (int dt = 0; dt < 4; dt++)
                O[dt] = __builtin_amdgcn_mfma_f32_16x16x32_bf16(
                    pa[kc], vf[kc * 4 + dt], O[dt], 0, 0, 0);
    };

    int t = 0;
    while (true) {
        body(t, kfa, kfb); if (++t == ntiles) break;
        body(t, kfb, kfa); if (++t == ntiles) break;
    }

    // combine the 4 quads' row-sum partials (same lane16 = same q-row)
    ps += __shfl_xor(ps, 16, 64);
    ps += __shfl_xor(ps, 32, 64);

    unsigned short* ob = att + ((size_t)(b * TT) + j * 16) * CC + h * DD;
#pragma unroll
    for (int r = 0; r < 4; r++) {
        float rl = 1.0f / __shfl(ps, quad * 4 + r, 16);
        int q = quad * 4 + r;
#pragma unroll
        for (int dt = 0; dt < 4; dt++)
            ob[(size_t)q * CC + dt * 16 + lane16] = f2b(O[dt][r] * rl);
    }
}

// ---------------------------------------------------------------------------
extern "C" void kernel_launch(void* const* d_in, const int* in_sizes, int n_in,
                              void* d_out, int out_size, void* d_ws, size_t ws_size,
                              hipStream_t stream) {
    const float* x     = (const float*)d_in[0];
    const float* Wqkv  = (const float*)d_in[1];
    const float* bqkv  = (const float*)d_in[2];
    const float* Wproj = (const float*)d_in[3];
    const float* bproj = (const float*)d_in[4];
    float* out = (float*)d_out;

    const size_t FRAG_ELEMS = (size_t)128 * 2 * 512;             // 131072 per bh
    unsigned short* xb      = (unsigned short*)d_ws;             // [4096][1024]
    unsigned short* Qf      = xb + (size_t)BT * CC;              // [32][131072]
    unsigned short* Kf      = Qf + (size_t)BB * HH * FRAG_ELEMS;
    unsigned short* Vf      = Kf + (size_t)BB * HH * FRAG_ELEMS;
    unsigned short* Wqkv_t  = Vf + (size_t)BB * HH * FRAG_ELEMS; // [3072][1024]
    unsigned short* Wproj_t = Wqkv_t + (size_t)C3 * CC;          // [1024][1024]
    unsigned short* att_b   = Wproj_t + (size_t)CC * CC;         // [4096][1024]

    // 1) input cast + weight transposes (one launch)
    prep_kernel<<<3072, 256, 0, stream>>>(x, xb, Wqkv, Wproj, Wqkv_t, Wproj_t);

    // 2) QKV GEMM -> fragment-ordered Qf/Kf/Vf (Q pre-scaled by log2(e)/8)
    {
        dim3 grid(C3 / 128, BT / 128);
        gemm_bt_kernel<unsigned short, true><<<grid, 256, 0, stream>>>(
            xb, Wqkv_t, bqkv, (unsigned short*)nullptr, Qf, Kf, Vf,
            BT, C3, CC, 0.125f * 1.44269504f);
    }
    // 3) flash attention (16-row q-tiles, single-wave blocks, 4 waves/SIMD)
    {
        dim3 grid(BB * HH, 128);
        attn_mfma_kernel<<<grid, 64, 0, stream>>>(Qf, Kf, Vf, att_b);
    }
    // 4) projection GEMM -> fp32 out
    {
        dim3 grid(CC / 128, BT / 128);
        gemm_bt_kernel<float, false><<<grid, 256, 0, stream>>>(
            att_b, Wproj_t, bproj, out, nullptr, nullptr, nullptr,
            BT, CC, CC, 1.0f);
    }
}

// Round 8
// 173.236 us; speedup vs baseline: 1.3527x; 1.3527x over previous
//
#include <hip/hip_runtime.h>
#include <hip/hip_bf16.h>
#include <math.h>

#define BB 2
#define TT 2048
#define CC 1024
#define HH 16
#define DD 64
#define C3 3072
#define BT 4096

typedef __attribute__((ext_vector_type(8))) short short8;
typedef __attribute__((ext_vector_type(8))) unsigned short ushort8;
typedef __attribute__((ext_vector_type(4))) unsigned short ushort4v;
typedef __attribute__((ext_vector_type(4))) float floatx4;

// fp32 -> bf16, round-to-nearest-even
__device__ __forceinline__ unsigned short f2b(float f) {
    union { float f; unsigned int u; } v; v.f = f;
    unsigned int u = v.u;
    unsigned int r = (u + 0x7fffu + ((u >> 16) & 1u)) >> 16;
    return (unsigned short)r;
}
// cheap round-half-up (for P weights; positive values)
__device__ __forceinline__ unsigned short f2b_fast(float f) {
    unsigned int u = __builtin_bit_cast(unsigned int, f);
    return (unsigned short)((u + 0x8000u) >> 16);
}

__device__ __forceinline__ void store_out(unsigned short* p, float v) { *p = f2b(v); }
__device__ __forceinline__ void store_out(float* p, float v) { *p = v; }

// async 16B global -> LDS (dest: wave-uniform base + lane*16)
__device__ __forceinline__ void async16(const unsigned short* g, unsigned short* lds) {
    __builtin_amdgcn_global_load_lds(
        (const __attribute__((address_space(1))) unsigned int*)g,
        (__attribute__((address_space(3))) unsigned int*)lds, 16, 0, 0);
}

// ---------------------------------------------------------------------------
// Prep kernel: blocks 0..2047 cast x fp32->bf16 (8 elems/thread);
// blocks 2048..3071 transpose+cast the two weight matrices (64x64 tiles).
// ---------------------------------------------------------------------------
__global__ __launch_bounds__(256) void prep_kernel(
    const float* __restrict__ x, unsigned short* __restrict__ xb,
    const float* __restrict__ Wqkv, const float* __restrict__ Wproj,
    unsigned short* __restrict__ Wqkv_t, unsigned short* __restrict__ Wproj_t)
{
    __shared__ float tile[64 * 65];
    const int tid = threadIdx.x;
    const int bid = blockIdx.x;

    if (bid < 2048) {                      // ---- cast x ----
        int i = bid * 256 + tid;
        const float4 v0 = *(const float4*)&x[(size_t)i * 8];
        const float4 v1 = *(const float4*)&x[(size_t)i * 8 + 4];
        ushort8 pk;
        pk[0] = f2b(v0.x); pk[1] = f2b(v0.y); pk[2] = f2b(v0.z); pk[3] = f2b(v0.w);
        pk[4] = f2b(v1.x); pk[5] = f2b(v1.y); pk[6] = f2b(v1.z); pk[7] = f2b(v1.w);
        *(ushort8*)&xb[(size_t)i * 8] = pk;
        return;
    }

    // ---- weight transposes ----
    const int xt = bid - 2048;             // 0..1023
    const int cxt = xt & 63;               // col-tile
    const int r0  = (xt >> 6) * 64;        // row-tile base
    const float* src; unsigned short* dst; int Ccols, c0;
    if (cxt < 48) { src = Wqkv;  dst = Wqkv_t;  Ccols = C3; c0 = cxt * 64; }
    else          { src = Wproj; dst = Wproj_t; Ccols = CC; c0 = (cxt - 48) * 64; }
#pragma unroll
    for (int it = 0; it < 4; it++) {
        int idx = it * 256 + tid;
        int row = idx >> 4;
        int c4  = idx & 15;
        float4 v = *(const float4*)&src[(size_t)(r0 + row) * Ccols + c0 + c4 * 4];
        tile[row * 65 + c4 * 4 + 0] = v.x;
        tile[row * 65 + c4 * 4 + 1] = v.y;
        tile[row * 65 + c4 * 4 + 2] = v.z;
        tile[row * 65 + c4 * 4 + 3] = v.w;
    }
    __syncthreads();
#pragma unroll
    for (int it = 0; it < 2; it++) {
        int idx = it * 256 + tid;
        int orow = idx >> 3;
        int o8   = idx & 7;
        ushort8 pk;
#pragma unroll
        for (int j = 0; j < 8; j++) pk[j] = f2b(tile[(o8 * 8 + j) * 65 + orow]);
        *(ushort8*)&dst[(size_t)(c0 + orow) * CC + r0 + o8 * 8] = pk;
    }
}

// ---------------------------------------------------------------------------
// bf16 GEMM, B transposed: 128x128, BK=64, XOR chunk swizzle.
// FRAG mode (QKV GEMM): write Q/K/V directly in MFMA-fragment order so
// attention reads are lane-contiguous 1KB chunks:
//   Qf/Kf[((bh*128 + tok/16)*2 + d/32)*512 + ((d/8)%4)*128 + (tok%16)*8 + d%8]
//   Vf  [((bh*64 + tok/32)*4 + d/16)*512 + ((tok/4)%4*16 + d%16)*8
//        + ((tok/16)%2)*4 + tok%4]     (key-slot permutation folded in)
// Q is pre-scaled by log2(e)/8.
// ---------------------------------------------------------------------------
template <typename OUT_T, bool FRAG>
__global__ __launch_bounds__(256) void gemm_bt_kernel(
    const unsigned short* __restrict__ A, const unsigned short* __restrict__ Bm,
    const float* __restrict__ bias, OUT_T* __restrict__ Cmat,
    unsigned short* __restrict__ Qf, unsigned short* __restrict__ Kf,
    unsigned short* __restrict__ Vf,
    int M, int N, int K, float qscale)
{
    __shared__ __align__(16) unsigned short sA[128 * 64];
    __shared__ __align__(16) unsigned short sB[128 * 64];

    const int tid = threadIdx.x;
    const int lane16 = tid & 15, quad = (tid & 63) >> 4;
    const int w = tid >> 6;
    const int wm = w >> 1, wn = w & 1;
    const int m0 = blockIdx.y * 128, n0 = blockIdx.x * 128;
    const int lx = lane16 & 7;

    floatx4 acc[4][4] = {};

    for (int kt = 0; kt < K; kt += 64) {
#pragma unroll
        for (int it = 0; it < 4; it++) {
            int idx = it * 256 + tid;
            int row = idx >> 3;
            int c8m = (idx & 7) ^ (row & 7);
            int wslot = it * 256 + (tid & 192);
            async16(&A[(size_t)(m0 + row) * K + kt + c8m * 8], &sA[wslot * 8]);
            async16(&Bm[(size_t)(n0 + row) * K + kt + c8m * 8], &sB[wslot * 8]);
        }
        __syncthreads();
#pragma unroll
        for (int ks = 0; ks < 64; ks += 32) {
            const int slot = ((ks >> 3) + quad) ^ lx;
            short8 af[4], bf[4];
#pragma unroll
            for (int t = 0; t < 4; t++) {
                af[t] = *(const short8*)&sA[(wm * 64 + t * 16 + lane16) * 64 + slot * 8];
                bf[t] = *(const short8*)&sB[(wn * 64 + t * 16 + lane16) * 64 + slot * 8];
            }
#pragma unroll
            for (int mt = 0; mt < 4; mt++)
#pragma unroll
                for (int nt = 0; nt < 4; nt++)
                    acc[mt][nt] = __builtin_amdgcn_mfma_f32_16x16x32_bf16(
                        af[mt], bf[nt], acc[mt][nt], 0, 0, 0);
        }
        __syncthreads();
    }

#pragma unroll
    for (int mt = 0; mt < 4; mt++) {
#pragma unroll
        for (int nt = 0; nt < 4; nt++) {
            int col = n0 + wn * 64 + nt * 16 + lane16;
            float bv = bias[col];
            int row0 = m0 + wm * 64 + mt * 16 + quad * 4;
            if (!FRAG) {
#pragma unroll
                for (int r = 0; r < 4; r++)
                    store_out(&Cmat[(size_t)(row0 + r) * N + col], acc[mt][nt][r] + bv);
            } else {
                const int breg = row0 >> 11;            // batch
                const int tok0 = row0 & (TT - 1);       // token (4-aligned)
                if (col < CC) {                          // ---- Q (scaled) ----
                    int h = col >> 6, d = col & 63;
                    int bh = breg * HH + h;
                    size_t base = ((size_t)(bh * 128 + (tok0 >> 4)) * 2 + (d >> 5)) * 512
                                + ((d >> 3) & 3) * 128 + (tok0 & 15) * 8 + (d & 7);
#pragma unroll
                    for (int r = 0; r < 4; r++)
                        Qf[base + r * 8] = f2b((acc[mt][nt][r] + bv) * qscale);
                } else if (col < 2 * CC) {               // ---- K ----
                    int c = col - CC;
                    int h = c >> 6, d = c & 63;
                    int bh = breg * HH + h;
                    size_t base = ((size_t)(bh * 128 + (tok0 >> 4)) * 2 + (d >> 5)) * 512
                                + ((d >> 3) & 3) * 128 + (tok0 & 15) * 8 + (d & 7);
#pragma unroll
                    for (int r = 0; r < 4; r++)
                        Kf[base + r * 8] = f2b(acc[mt][nt][r] + bv);
                } else {                                 // ---- V ----
                    int c = col - 2 * CC;
                    int h = c >> 6, d = c & 63;
                    int bh = breg * HH + h;
                    size_t base = ((size_t)(bh * 64 + (tok0 >> 5)) * 4 + (d >> 4)) * 512
                                + (((tok0 >> 2) & 3) * 16 + (d & 15)) * 8
                                + ((tok0 >> 4) & 1) * 4;
                    ushort4v pk;
#pragma unroll
                    for (int r = 0; r < 4; r++) pk[r] = f2b(acc[mt][nt][r] + bv);
                    *(ushort4v*)&Vf[base] = pk;
                }
            }
        }
    }
}

// ---------------------------------------------------------------------------
// Flash attention, R8: 4-wave block / 64-row q-tile (wave w owns rows
// qw=q0+16w), K/V staged per tile into LDS in FRAGMENT-CHUNK order via
// global_load_lds (async DMA, no VGPR round-trip). Every LDS read is a
// lane-linear ds_read_b128 (addr = chunk + lane*16B) -> ZERO bank conflicts
// (R3's 6.5M conflict cycles came from strided row-major reads).
// Double-buffered, ONE barrier/tile; the barrier's vmcnt drain is the
// async-stage fence. No forced occupancy bounds (R7's launch_bounds(64,4)
// clamped VGPR to 64 -> 124MB scratch spill).
// Swapped QK^T + in-register P (R3/R4-verified math). Grid (32 bh, 32 y),
// balanced p-map, XCD-local heads. Q pre-scaled by log2(e)/8 in GEMM1.
// ---------------------------------------------------------------------------
__global__ __launch_bounds__(256) void attn_mfma_kernel(
    const unsigned short* __restrict__ Qf, const unsigned short* __restrict__ Kf,
    const unsigned short* __restrict__ Vf, unsigned short* __restrict__ att)
{
    __shared__ __align__(16) unsigned short Ks[2][8 * 512];   // 8KB per buf
    __shared__ __align__(16) unsigned short Vs[2][8 * 512];   // 8KB per buf

    const int tid = threadIdx.x;
    const int l = tid & 63;
    const int w = tid >> 6;
    const int lane16 = l & 15, quad = l >> 4;
    const int bh = blockIdx.x;                    // same head -> same XCD
    const int b = bh >> 4, h = bh & 15;

    // balanced q-tile assignment (every CU's 4 blocks sum to 66 tile-units)
    const int y = blockIdx.y;                     // 0..31
    const int gcu = y & 7, s = y >> 3;
    const int p = 8 * s + ((s & 1) ? (7 - gcu) : gcu);
    const int q0 = p * 64;
    const int qw = q0 + w * 16;                   // this wave's 16 q-rows

    const unsigned short* Qb  = Qf + (size_t)bh * 131072 + l * 8;
    const unsigned short* KbT = Kf + (size_t)bh * 131072;
    const unsigned short* VbT = Vf + (size_t)bh * 131072;

    // Q fragments (B-operand layout: n=lane16=q, k=quad*8+j=d)
    short8 qf0 = *(const short8*)&Qb[(size_t)((qw >> 4) * 2 + 0) * 512];
    short8 qf1 = *(const short8*)&Qb[(size_t)((qw >> 4) * 2 + 1) * 512];

    floatx4 O[4] = {};                            // [dt]
    float ps = 0.f;                               // row-sum partial
    const int ntiles = p + 1;
    const int qrow = qw + lane16;                 // this lane's global q row

    // stage tile tt into LDS buffer buf: 16 chunks (K:0..7, V:8..15) split
    // 4 per wave; async16 dest = wave-uniform chunk base (+HW lane*16)
    auto stage = [&](int tt, int buf) {
#pragma unroll
        for (int s4 = 0; s4 < 4; s4++) {
            int c = s4 * 4 + w;
            if (c < 8)
                async16(&KbT[((size_t)tt * 8 + c) * 512 + l * 8], &Ks[buf][c * 512]);
            else
                async16(&VbT[((size_t)tt * 8 + (c - 8)) * 512 + l * 8], &Vs[buf][(c - 8) * 512]);
        }
    };

    stage(0, 0);
    __syncthreads();                              // drain stage of tile 0

    int cur = 0;
    for (int t = 0; t < ntiles; ++t) {
        if (t + 1 < ntiles) stage(t + 1, cur ^ 1);   // async into other buffer

        // ---- K fragments from LDS (lane-linear b128, conflict-free) ----
        short8 kf[8];
#pragma unroll
        for (int i = 0; i < 8; i++)
            kf[i] = *(const short8*)&Ks[cur][i * 512 + l * 8];

        // ---- S^T = K Q^T ; p = exp2(s); pack P as PV A-frag words ----
        const bool last = (t == ntiles - 1);
        short8 pa[2];                             // [kc]
#pragma unroll
        for (int nt = 0; nt < 4; nt++) {
            floatx4 s4v = {};
            s4v = __builtin_amdgcn_mfma_f32_16x16x32_bf16(kf[nt * 2 + 0], qf0, s4v, 0, 0, 0);
            s4v = __builtin_amdgcn_mfma_f32_16x16x32_bf16(kf[nt * 2 + 1], qf1, s4v, 0, 0, 0);
#pragma unroll
            for (int r = 0; r < 4; r++) {
                float v = s4v[r];
                if (last) {                       // diag tile: causal mask
                    int key = t * 64 + nt * 16 + quad * 4 + r;
                    if (key > qrow) v = -1e30f;
                }
                float pe = __builtin_amdgcn_exp2f(v);
                ps += pe;
                pa[nt >> 1][(nt & 1) * 4 + r] = (short)f2b_fast(pe);
            }
        }

        // ---- O += P V (V fragments from LDS, lane-linear b128) ----
#pragma unroll
        for (int kc = 0; kc < 2; kc++) {
            short8 vfr[4];
#pragma unroll
            for (int i = 0; i < 4; i++)
                vfr[i] = *(const short8*)&Vs[cur][(kc * 4 + i) * 512 + l * 8];
#pragma unroll
            for (int dt = 0; dt < 4; dt++)
                O[dt] = __builtin_amdgcn_mfma_f32_16x16x32_bf16(
                    pa[kc], vfr[dt], O[dt], 0, 0, 0);
        }

        __syncthreads();   // LDS reads done + next-tile stage drained (vmcnt)
        cur ^= 1;
    }

    // combine the 4 quads' row-sum partials (same lane16 = same q-row)
    ps += __shfl_xor(ps, 16, 64);
    ps += __shfl_xor(ps, 32, 64);

    unsigned short* ob = att + ((size_t)(b * TT) + qw) * CC + h * DD;
#pragma unroll
    for (int r = 0; r < 4; r++) {
        float rl = 1.0f / __shfl(ps, quad * 4 + r, 16);
        int q = quad * 4 + r;
#pragma unroll
        for (int dt = 0; dt < 4; dt++)
            ob[(size_t)q * CC + dt * 16 + lane16] = f2b(O[dt][r] * rl);
    }
}

// ---------------------------------------------------------------------------
extern "C" void kernel_launch(void* const* d_in, const int* in_sizes, int n_in,
                              void* d_out, int out_size, void* d_ws, size_t ws_size,
                              hipStream_t stream) {
    const float* x     = (const float*)d_in[0];
    const float* Wqkv  = (const float*)d_in[1];
    const float* bqkv  = (const float*)d_in[2];
    const float* Wproj = (const float*)d_in[3];
    const float* bproj = (const float*)d_in[4];
    float* out = (float*)d_out;

    const size_t FRAG_ELEMS = (size_t)128 * 2 * 512;             // 131072 per bh
    unsigned short* xb      = (unsigned short*)d_ws;             // [4096][1024]
    unsigned short* Qf      = xb + (size_t)BT * CC;              // [32][131072]
    unsigned short* Kf      = Qf + (size_t)BB * HH * FRAG_ELEMS;
    unsigned short* Vf      = Kf + (size_t)BB * HH * FRAG_ELEMS;
    unsigned short* Wqkv_t  = Vf + (size_t)BB * HH * FRAG_ELEMS; // [3072][1024]
    unsigned short* Wproj_t = Wqkv_t + (size_t)C3 * CC;          // [1024][1024]
    unsigned short* att_b   = Wproj_t + (size_t)CC * CC;         // [4096][1024]

    // 1) input cast + weight transposes (one launch)
    prep_kernel<<<3072, 256, 0, stream>>>(x, xb, Wqkv, Wproj, Wqkv_t, Wproj_t);

    // 2) QKV GEMM -> fragment-ordered Qf/Kf/Vf (Q pre-scaled by log2(e)/8)
    {
        dim3 grid(C3 / 128, BT / 128);
        gemm_bt_kernel<unsigned short, true><<<grid, 256, 0, stream>>>(
            xb, Wqkv_t, bqkv, (unsigned short*)nullptr, Qf, Kf, Vf,
            BT, C3, CC, 0.125f * 1.44269504f);
    }
    // 3) flash attention (4-wave blocks, async fragment-chunk LDS staging)
    {
        dim3 grid(BB * HH, 32);
        attn_mfma_kernel<<<grid, 256, 0, stream>>>(Qf, Kf, Vf, att_b);
    }
    // 4) projection GEMM -> fp32 out
    {
        dim3 grid(CC / 128, BT / 128);
        gemm_bt_kernel<float, false><<<grid, 256, 0, stream>>>(
            att_b, Wproj_t, bproj, out, nullptr, nullptr, nullptr,
            BT, CC, CC, 1.0f);
    }
}